// Round 1
// baseline (198.897 us; speedup 1.0000x reference)
//
#include <hip/hip_runtime.h>

// CBC (classification-by-components) fused kernel, v2.
// x:[B,1024] f32, components:[5,1024] f32, reasonings:[5,3,2] f32 -> probs:[B,3] f32.
//
// Structure: each 64-lane wave splits into 4 segments of 16 lanes; each segment
// owns one row -> 4 rows per wave-iteration ("group"). Each lane loads 16
// float4 (one per j-step) covering its row; inside the j-loop the consumed
// register is immediately refilled with the NEXT group's load, keeping 16
// dwordx4 (16 KB/wave) in flight at all times. Components live in LDS (20 KB)
// instead of 80 VGPRs, freeing registers for the deep load buffer.
// d^2 via expansion (x2 + c2 - 2*dot), clamped at 0, matching the reference.

#define DD 1024
#define KK 5
#define CC 3
#define F4R (DD / 4)   // 256 float4 per row
#define JS 16          // j-steps per group: 256 float4 / 16 lanes

__global__ __launch_bounds__(256, 2) void cbc_kernel(
    const float* __restrict__ x,
    const float* __restrict__ comps,
    const float* __restrict__ reas,
    float* __restrict__ out,
    int B)
{
    __shared__ float4 cl[KK * F4R];   // 20480 B

    const int tid  = threadIdx.x;
    const int lane = tid & 63;
    const int seg  = lane >> 4;       // which of the wave's 4 rows
    const int t    = lane & 15;       // col4 index within a j-step

    const int waves_per_block = blockDim.x >> 6;
    const int wave    = blockIdx.x * waves_per_block + (tid >> 6);
    const int n_waves = gridDim.x * waves_per_block;

    // ---- stage components into LDS (coalesced float4) ----
    const float4* c4 = (const float4*)comps;
    for (int i = tid; i < KK * F4R; i += blockDim.x) cl[i] = c4[i];

    // ---- per-lane reasoning params, only for this lane's class c = t ----
    // pk = A; nk = (1-A)*B; w = pk-nk; bias = sum nk; den = sum (pk+nk)
    const int c = (t < CC) ? t : 0;
    float wv[KK], bias = 0.f, den = 0.f;
#pragma unroll
    for (int k = 0; k < KK; ++k) {
        float a = reas[k * (CC * 2) + c * 2 + 0];
        float b = reas[k * (CC * 2) + c * 2 + 1];
        a = fminf(fmaxf(a, 0.f), 1.f);
        b = fminf(fmaxf(b, 0.f), 1.f);
        float nk = (1.f - a) * b;
        wv[k] = a - nk;
        bias += nk;
        den  += a + nk;
    }
    const float invden = 1.f / den;

    __syncthreads();

    const float4* x4 = (const float4*)x;
    const int ngroups = B >> 2;   // 4 rows per group

    int g = wave;
    if (g < ngroups) {
        // ---- prologue: issue all 16 loads of the first group ----
        float4 xb[JS];
        {
            int row = g * 4 + seg; if (row >= B) row = B - 1;
            const float4* p = x4 + (size_t)row * F4R + t;
#pragma unroll
            for (int j = 0; j < JS; ++j) xb[j] = p[j * 16];
        }

        // ---- c2[k] = |comp_k|^2, computed once (overlaps prologue latency) ----
        float c2[KK];
#pragma unroll
        for (int k = 0; k < KK; ++k) c2[k] = 0.f;
#pragma unroll
        for (int j = 0; j < JS; ++j) {
#pragma unroll
            for (int k = 0; k < KK; ++k) {
                float4 cv = cl[k * F4R + j * 16 + t];
                c2[k] += cv.x * cv.x; c2[k] += cv.y * cv.y;
                c2[k] += cv.z * cv.z; c2[k] += cv.w * cv.w;
            }
        }
#pragma unroll
        for (int k = 0; k < KK; ++k)
#pragma unroll
            for (int off = 1; off < 16; off <<= 1)
                c2[k] += __shfl_xor(c2[k], off, 64);

        // ---- main loop over groups (grid-stride), 2 iterations at B=32768 ----
        while (true) {
            const int  gn = g + n_waves;
            const bool hn = gn < ngroups;

            float dot[KK], x2 = 0.f;
#pragma unroll
            for (int k = 0; k < KK; ++k) dot[k] = 0.f;

            if (hn) {
                // steady state: refill xb[j] with next group's load right after use
                int nrow = gn * 4 + seg; if (nrow >= B) nrow = B - 1;
                const float4* np = x4 + (size_t)nrow * F4R + t;
#pragma unroll
                for (int j = 0; j < JS; ++j) {
                    float4 xv = xb[j];
                    xb[j] = np[j * 16];          // prefetch next group
#pragma unroll
                    for (int k = 0; k < KK; ++k) {
                        float4 cv = cl[k * F4R + j * 16 + t];
                        dot[k] += xv.x * cv.x; dot[k] += xv.y * cv.y;
                        dot[k] += xv.z * cv.z; dot[k] += xv.w * cv.w;
                    }
                    x2 += xv.x * xv.x; x2 += xv.y * xv.y;
                    x2 += xv.z * xv.z; x2 += xv.w * xv.w;
                }
            } else {
                // last group: no prefetch (avoids redundant HBM traffic)
#pragma unroll
                for (int j = 0; j < JS; ++j) {
                    float4 xv = xb[j];
#pragma unroll
                    for (int k = 0; k < KK; ++k) {
                        float4 cv = cl[k * F4R + j * 16 + t];
                        dot[k] += xv.x * cv.x; dot[k] += xv.y * cv.y;
                        dot[k] += xv.z * cv.z; dot[k] += xv.w * cv.w;
                    }
                    x2 += xv.x * xv.x; x2 += xv.y * xv.y;
                    x2 += xv.z * xv.z; x2 += xv.w * xv.w;
                }
            }

            // ---- 16-lane segment reductions (masks 1,2,4,8 stay in-segment) ----
#pragma unroll
            for (int off = 1; off < 16; off <<= 1)
                x2 += __shfl_xor(x2, off, 64);
#pragma unroll
            for (int k = 0; k < KK; ++k)
#pragma unroll
                for (int off = 1; off < 16; off <<= 1)
                    dot[k] += __shfl_xor(dot[k], off, 64);

            // ---- epilogue: 3 lanes per segment write this row's 3 probs ----
            const int row = g * 4 + seg;
            if (t < CC && row < B) {
                float num = bias;
#pragma unroll
                for (int k = 0; k < KK; ++k) {
                    float d2 = x2 + c2[k] - 2.f * dot[k];
                    d2 = fmaxf(d2, 0.f);
                    num += __expf(-0.5f * d2) * wv[k];   // variance = 1
                }
                out[(size_t)row * CC + t] = num * invden;
            }

            if (!hn) break;
            g = gn;
        }
    }
}

extern "C" void kernel_launch(void* const* d_in, const int* in_sizes, int n_in,
                              void* d_out, int out_size, void* d_ws, size_t ws_size,
                              hipStream_t stream) {
    const float* x = (const float*)d_in[0];
    const float* comps = (const float*)d_in[1];
    const float* reas = (const float*)d_in[2];
    float* out = (float*)d_out;
    const int B = in_sizes[0] / (DD * 4);   // bytes -> rows? (see below)

    // in_sizes is in elements in this harness (B*DD floats): keep the original
    // convention from the working baseline kernel:
    const int Brows = in_sizes[0] / DD;     // 32768

    // 1024 blocks x 256 threads = 4096 waves; 8192 groups -> 2 groups/wave,
    // giving one full prefetch-overlapped steady-state iteration per wave.
    const int blocks = 1024;
    cbc_kernel<<<blocks, 256, 0, stream>>>(x, comps, reas, out, Brows);
    (void)B;
}